// Round 1
// baseline (2043.639 us; speedup 1.0000x reference)
//
#include <hip/hip_runtime.h>

// V=10000, R=8192, D=1024, B=1024, L=64, M=65536
// R10 = R9 (1280 us) with the 64 k_step_mfma launches (~600 us aggregate)
// replaced by ONE persistent cooperative kernel k_rnn:
//  - Whh held in registers (32 s8v/lane = exact MFMA B-frags for the wave's
//    16 cols x K=1024) -> loaded once, zero staging for 64 steps.
//  - per step only A (h_{t-1}) staged: 8 chunks of BK=128 into XOR-swizzled
//    LDS (old [.][32] layout was an 8-way ds_read_b128 conflict; swizzled
//    16B slots -> 2-way = free), reg prefetch, 16 barriers/step (was 64).
//  - grid sync: monotone counter, release fetch_add (wbl2 -> data reaches LLC
//    so cross-XCD readers are safe) + relaxed agent spin. No acquire-inv
//    needed: each step reads a fresh (t-1) slice no reader ever cached.
//  - block decode r=bx&31 => all blocks of a row-group land on XCD r%8
//    (bx%8), so h row-tiles are produced AND consumed in the same L2 (perf
//    heuristic only; correctness holds for any mapping via the release).
#define D_DIM   1024
#define L_SEQ   64
#define B_BATCH 1024
#define M_NODES 65536
#define R_RULES 8192
#define V_VOCAB 10000
#define NBLK_RNN 256

typedef unsigned short bf16_t;
typedef __attribute__((ext_vector_type(8))) short s8v;   // 8 bf16 (MFMA A/B frag)
typedef __attribute__((ext_vector_type(4))) short s4v;   // 4 bf16
typedef __attribute__((ext_vector_type(4))) float f4v;   // MFMA C/D frag

static __device__ __forceinline__ float bf2f(unsigned short u) {
    union { unsigned int i; float f; } v; v.i = ((unsigned int)u) << 16; return v.f;
}
static __device__ __forceinline__ unsigned short f2bf(float f) {  // RNE
    union { float f; unsigned int i; } v; v.f = f;
    return (unsigned short)((v.i + 0x7FFFu + ((v.i >> 16) & 1u)) >> 16);
}
static __device__ __forceinline__ float fast_tanh(float x) {
    float xc = fminf(fmaxf(x, -15.f), 15.f);
    float t  = __expf(2.f * xc);
    return (t - 1.f) * __builtin_amdgcn_rcpf(t + 1.f);
}

static __device__ __forceinline__ f4v mfma16(s8v a, s8v b, f4v c) {
    return __builtin_amdgcn_mfma_f32_16x16x32_bf16(a, b, c, 0, 0, 0);
}

// ---------------------------------------------------------------------------
__global__ __launch_bounds__(256) void k_cvt_emb(
    const float* __restrict__ emb, bf16_t* __restrict__ embB)
{
    size_t i = ((size_t)blockIdx.x * 256 + threadIdx.x) * 8;
    f4v x0 = *(const f4v*)&emb[i];
    f4v x1 = *(const f4v*)&emb[i + 4];
    s8v o;
    o[0] = (short)f2bf(x0.x); o[1] = (short)f2bf(x0.y);
    o[2] = (short)f2bf(x0.z); o[3] = (short)f2bf(x0.w);
    o[4] = (short)f2bf(x1.x); o[5] = (short)f2bf(x1.y);
    o[6] = (short)f2bf(x1.z); o[7] = (short)f2bf(x1.w);
    *(s8v*)&embB[i] = o;
}

__global__ __launch_bounds__(256) void k_transcvt(
    const float* __restrict__ src, bf16_t* __restrict__ dst, int K, int N)
{
    __shared__ float s[32][33];
    int n0 = blockIdx.x * 32, k0 = blockIdx.y * 32;
    int tx = threadIdx.x, ty = threadIdx.y;  // (32,8)
#pragma unroll
    for (int i = 0; i < 4; ++i)
        s[ty + i * 8][tx] = src[(size_t)(k0 + ty + i * 8) * N + n0 + tx];
    __syncthreads();
#pragma unroll
    for (int i = 0; i < 4; ++i)
        dst[(size_t)(n0 + ty + i * 8) * K + k0 + tx] = f2bf(s[tx][ty + i * 8]);
}

__global__ __launch_bounds__(256) void k_cvt_h0(
    const float* __restrict__ h0, bf16_t* __restrict__ h0b, int* __restrict__ bar)
{
    if (threadIdx.x == 0) *bar = 0;     // reset grid-barrier counter each launch
    for (int u = threadIdx.x; u < D_DIM; u += 256) h0b[u] = f2bf(h0[u]);
}

// ---------------------------------------------------------------------------
// k_xw_mfma: XE[n,:] = bf16(embB[tokens[n],:] @ Wxh + bh)
// 128x128 tile, BK=32, manual staging + VGPR prefetch, XCD swizzle.
// ---------------------------------------------------------------------------
__global__ __launch_bounds__(256) void k_xw_mfma(
    const int* __restrict__ tokens, const bf16_t* __restrict__ embB,
    const bf16_t* __restrict__ WxhT, const float* __restrict__ bh,
    bf16_t* __restrict__ XE)
{
    __shared__ bf16_t As[128 * 32];            // 8 KB
    __shared__ bf16_t Bs[128 * 32];            // 8 KB
    __shared__ float  epi[4][16][68];          // 17.4 KB (per-wave private)

    const int bi  = blockIdx.x;
    const int xcd = bi & 7, j = bi >> 3;
    const int row0 = ((xcd << 6) + (j >> 3)) * 128;   // rowTile in [0,512)
    const int col0 = (j & 7) * 128;                   // colTile in [0,8)

    const int tid = threadIdx.x;
    const int w = tid >> 6, l = tid & 63;
    const int q = l >> 4, t16 = l & 15;
    const int wm = (w >> 1) * 64, wn = (w & 1) * 64;

    const bf16_t* arow[2];
#pragma unroll
    for (int r = 0; r < 2; ++r)
        arow[r] = embB + (size_t)tokens[row0 + (tid >> 2) + r * 64] * D_DIM + ((tid & 3) << 3);
    const bf16_t* brow[2];
#pragma unroll
    for (int r = 0; r < 2; ++r)
        brow[r] = WxhT + (size_t)(col0 + (tid >> 2) + r * 64) * D_DIM + ((tid & 3) << 3);

    f4v acc[4][4];
#pragma unroll
    for (int i = 0; i < 4; ++i)
#pragma unroll
        for (int jj = 0; jj < 4; ++jj) acc[i][jj] = (f4v)0.f;

    // prefetch k=0
    s8v a0 = *(const s8v*)(arow[0]);
    s8v a1 = *(const s8v*)(arow[1]);
    s8v b0 = *(const s8v*)(brow[0]);
    s8v b1 = *(const s8v*)(brow[1]);

    const int rr = tid >> 2, cc = (tid & 3) << 3;
    for (int k0 = 0; k0 < D_DIM; k0 += 32) {
        __syncthreads();                       // prev iter frag reads done
        *(s8v*)&As[rr * 32 + cc]        = a0;
        *(s8v*)&As[(rr + 64) * 32 + cc] = a1;
        *(s8v*)&Bs[rr * 32 + cc]        = b0;
        *(s8v*)&Bs[(rr + 64) * 32 + cc] = b1;
        int kn = k0 + 32;
        if (kn < D_DIM) {                      // issue next loads early
            a0 = *(const s8v*)(arow[0] + kn);
            a1 = *(const s8v*)(arow[1] + kn);
            b0 = *(const s8v*)(brow[0] + kn);
            b1 = *(const s8v*)(brow[1] + kn);
        }
        __syncthreads();
        s8v af[4], bfr[4];
#pragma unroll
        for (int ti = 0; ti < 4; ++ti)
            af[ti] = *(const s8v*)&As[(wm + ti * 16 + t16) * 32 + q * 8];
#pragma unroll
        for (int tj = 0; tj < 4; ++tj)
            bfr[tj] = *(const s8v*)&Bs[(wn + tj * 16 + t16) * 32 + q * 8];
#pragma unroll
        for (int ti = 0; ti < 4; ++ti)
#pragma unroll
            for (int tj = 0; tj < 4; ++tj)
                acc[ti][tj] = mfma16(af[ti], bfr[tj], acc[ti][tj]);
    }

    // barrier-free per-wave epilogue (epi[w] wave-private)
    const int lr = l >> 2, c16 = (l & 3) * 16;
    f4v bias[4];
#pragma unroll
    for (int u = 0; u < 4; ++u)
        bias[u] = *(const f4v*)&bh[col0 + wn + c16 + u * 4];
#pragma unroll
    for (int ti = 0; ti < 4; ++ti) {
#pragma unroll
        for (int tj = 0; tj < 4; ++tj)
#pragma unroll
            for (int rg = 0; rg < 4; ++rg)
                epi[w][q * 4 + rg][tj * 16 + t16] = acc[ti][tj][rg];
        s8v o0, o1;
#pragma unroll
        for (int u = 0; u < 8; ++u) {
            o0[u] = (short)f2bf(epi[w][lr][c16 + u]     + bias[u >> 2][u & 3]);
            o1[u] = (short)f2bf(epi[w][lr][c16 + 8 + u] + bias[2 + (u >> 2)][u & 3]);
        }
        size_t orow = (size_t)(row0 + wm + ti * 16 + lr) * D_DIM + col0 + wn + c16;
        *(s8v*)&XE[orow]     = o0;
        *(s8v*)&XE[orow + 8] = o1;
    }
}

// ---------------------------------------------------------------------------
// k_rnn: persistent cooperative kernel, all 64 RNN steps.
//   y = tanh(XE[b*L+t,:] + h_prev[b,:] @ Whh); XE[b*L+t,:] = bf16(y)
// Grid 256 = 32 row-groups (32 batch rows) x 8 col-groups (128 cols).
// 512 threads = 8 waves; wave w owns cols [col0+w*16, +16), rows all 32.
// B-frags (WhhT) in 128 VGPRs/lane, loaded once. A staged per step in
// XOR-swizzled LDS (2-way conflict-free ds_read_b128), BK=128 x 8 chunks.
// ---------------------------------------------------------------------------
__global__ __launch_bounds__(512, 2) void k_rnn(
    const bf16_t* __restrict__ h0b, const bf16_t* __restrict__ WhhT,
    bf16_t* __restrict__ XE, int* __restrict__ bar)
{
    __shared__ bf16_t As[32 * 128];        // 8 KB, 16B slots XOR-swizzled by row&7
    __shared__ float  epi[8][16][20];      // 10.2 KB (per-wave private)

    const int bx   = blockIdx.x;
    const int rgp  = bx & 31;              // row-group; XCD = bx%8 = rgp%8
    const int cgp  = bx >> 5;              // col-group [0,8)
    const int row0 = rgp * 32;
    const int col0 = cgp * 128;

    const int tid = threadIdx.x;
    const int w = tid >> 6, l = tid & 63;
    const int q = l >> 4, t16 = l & 15;

    // ---- B preload: this lane's exact MFMA B-frags for cols (col0+w*16+t16),
    // all K=1024 -> 32 s8v = 128 VGPRs. One-time cost.
    s8v breg[32];
    {
        const bf16_t* bp = WhhT + (size_t)(col0 + w * 16 + t16) * D_DIM + q * 8;
#pragma unroll
        for (int kc = 0; kc < 32; ++kc)
            breg[kc] = *(const s8v*)(bp + kc * 32);
    }

    // ---- A staging geometry: thread (arow, aslot) stages 16B of row arow.
    // LDS slot = aslot ^ (arow&7)  (same XOR on read -> 2-way = free).
    const int arow = tid >> 4, aslot = tid & 15;
    bf16_t* awr = As + arow * 128 + ((aslot ^ (arow & 7)) << 3);
    const int rx = t16 & 7;
    const bf16_t* ard0 = As + t16 * 128;          // rows t16 and 16+t16
    const bf16_t* ard1 = As + (16 + t16) * 128;   // (16+t16)&7 == t16&7

    const size_t xrowA = (size_t)(row0 + arow) * (L_SEQ * D_DIM) + aslot * 8;
    const int lr = l >> 2, c4 = (l & 3) * 4;

    for (int t = 0; t < L_SEQ; ++t) {
        const bf16_t* asrc = (t == 0) ? (h0b + aslot * 8)
                                      : (XE + xrowA + (size_t)(t - 1) * D_DIM);
        f4v acc0 = (f4v)0.f, acc1 = (f4v)0.f;
        s8v rA = *(const s8v*)asrc;                    // chunk 0 prefetch
#pragma unroll
        for (int cch = 0; cch < 8; ++cch) {
            __syncthreads();                           // frag reads of prev chunk done
            *(s8v*)awr = rA;
            if (cch < 7) rA = *(const s8v*)(asrc + (cch + 1) * 128);
            __syncthreads();
#pragma unroll
            for (int kk = 0; kk < 4; ++kk) {
                const int sl = (((kk * 4 + q) ^ rx)) << 3;
                s8v a0 = *(const s8v*)(ard0 + sl);
                s8v a1 = *(const s8v*)(ard1 + sl);
                acc0 = mfma16(a0, breg[cch * 4 + kk], acc0);
                acc1 = mfma16(a1, breg[cch * 4 + kk], acc1);
            }
        }
        // epilogue: wave-private transpose, add u_t, tanh, store bf16 (in place)
#pragma unroll
        for (int ti = 0; ti < 2; ++ti) {
            f4v a = (ti == 0) ? acc0 : acc1;
#pragma unroll
            for (int rgi = 0; rgi < 4; ++rgi)
                epi[w][q * 4 + rgi][t16] = a[rgi];
            f4v v = *(const f4v*)&epi[w][lr][c4];
            int brow = row0 + ti * 16 + lr;
            size_t xi = ((size_t)brow * L_SEQ + t) * D_DIM + col0 + w * 16 + c4;
            s4v x = *(const s4v*)&XE[xi];
            s4v o;
#pragma unroll
            for (int u = 0; u < 4; ++u)
                o[u] = (short)f2bf(fast_tanh(bf2f((unsigned short)x[u]) + v[u]));
            *(s4v*)&XE[xi] = o;
        }
        // grid barrier (monotone counter; no reset race, lap impossible).
        // Release fetch_add flushes this XCD's dirty L2 lines to LLC, so a
        // reader on ANY XCD (whose L2 never cached the fresh t-slice) sees
        // them; relaxed agent-scope spin bypasses L1/L2.
        if (t < L_SEQ - 1) {
            __syncthreads();                 // all waves' h_t stores drained (vmcnt)
            if (tid == 0) {
                __hip_atomic_fetch_add(bar, 1, __ATOMIC_RELEASE, __HIP_MEMORY_SCOPE_AGENT);
                const int target = NBLK_RNN * (t + 1);
                while (__hip_atomic_load(bar, __ATOMIC_RELAXED, __HIP_MEMORY_SCOPE_AGENT) < target)
                    __builtin_amdgcn_s_sleep(2);
            }
            __syncthreads();
        }
    }
}

// ---------------------------------------------------------------------------
// k_mlp_mfma: h = tanh(concat(XE[i],XE[j]) @ W1 + b1) fused with rule-dot.
// 128x128 tile, K=2048, manual staging + prefetch, XCD swizzle.
// ---------------------------------------------------------------------------
__global__ __launch_bounds__(256) void k_mlp_mfma(
    const int* __restrict__ i_idx, const int* __restrict__ j_idx,
    const bf16_t* __restrict__ XE, const bf16_t* __restrict__ W1T,
    const float* __restrict__ b1, const bf16_t* __restrict__ Wt2,
    const int* __restrict__ r_idx, float* __restrict__ partials)
{
    __shared__ bf16_t As[128 * 32];            // 8 KB
    __shared__ bf16_t Bs[128 * 32];            // 8 KB

    const int bi  = blockIdx.x;
    const int xcd = bi & 7, j = bi >> 3;
    const int rowTile = (xcd << 6) + (j >> 3);        // [0,512)
    const int colTile = j & 7;                        // [0,8)
    const int row0 = rowTile * 128, col0 = colTile * 128;

    const int tid = threadIdx.x;
    const int w = tid >> 6, l = tid & 63;
    const int q = l >> 4, t16 = l & 15;
    const int wm = (w >> 1) * 64, wn = (w & 1) * 64;

    const bf16_t* pi[2]; const bf16_t* pj[2];
#pragma unroll
    for (int r = 0; r < 2; ++r) {
        int m = row0 + (tid >> 2) + r * 64;
        pi[r] = XE + (size_t)i_idx[m] * D_DIM + ((tid & 3) << 3);
        pj[r] = XE + (size_t)j_idx[m] * D_DIM - D_DIM + ((tid & 3) << 3);  // k in [1024,2048)
    }
    const bf16_t* brow[2];
#pragma unroll
    for (int r = 0; r < 2; ++r)
        brow[r] = W1T + (size_t)(col0 + (tid >> 2) + r * 64) * (2 * D_DIM) + ((tid & 3) << 3);

    f4v acc[4][4];
#pragma unroll
    for (int i = 0; i < 4; ++i)
#pragma unroll
        for (int jj = 0; jj < 4; ++jj) acc[i][jj] = (f4v)0.f;

    // prefetch k=0
    s8v a0 = *(const s8v*)(pi[0]);
    s8v a1 = *(const s8v*)(pi[1]);
    s8v b0 = *(const s8v*)(brow[0]);
    s8v b1v = *(const s8v*)(brow[1]);

    const int rr = tid >> 2, cc = (tid & 3) << 3;
    for (int k0 = 0; k0 < 2 * D_DIM; k0 += 32) {
        __syncthreads();
        *(s8v*)&As[rr * 32 + cc]        = a0;
        *(s8v*)&As[(rr + 64) * 32 + cc] = a1;
        *(s8v*)&Bs[rr * 32 + cc]        = b0;
        *(s8v*)&Bs[(rr + 64) * 32 + cc] = b1v;
        int kn = k0 + 32;
        if (kn < 2 * D_DIM) {
            a0  = *(const s8v*)(((kn < D_DIM) ? pi[0] : pj[0]) + kn);
            a1  = *(const s8v*)(((kn < D_DIM) ? pi[1] : pj[1]) + kn);
            b0  = *(const s8v*)(brow[0] + kn);
            b1v = *(const s8v*)(brow[1] + kn);
        }
        __syncthreads();
        s8v af[4], bfr[4];
#pragma unroll
        for (int ti = 0; ti < 4; ++ti)
            af[ti] = *(const s8v*)&As[(wm + ti * 16 + t16) * 32 + q * 8];
#pragma unroll
        for (int tj = 0; tj < 4; ++tj)
            bfr[tj] = *(const s8v*)&Bs[(wn + tj * 16 + t16) * 32 + q * 8];
#pragma unroll
        for (int ti = 0; ti < 4; ++ti)
#pragma unroll
            for (int tj = 0; tj < 4; ++tj)
                acc[ti][tj] = mfma16(af[ti], bfr[tj], acc[ti][tj]);
    }

    // fused epilogue in C-layout: fast_tanh, dot with gathered rule row, 16-lane reduce
    const int cb = colTile * 2 + (w & 1);
#pragma unroll
    for (int ti = 0; ti < 4; ++ti) {
#pragma unroll
        for (int rg = 0; rg < 4; ++rg) {
            int m = row0 + wm + ti * 16 + q * 4 + rg;
            int r = r_idx[m];
            const bf16_t* wrow = Wt2 + (size_t)r * D_DIM + col0 + wn + t16;
            float pd = 0.f;
#pragma unroll
            for (int tj = 0; tj < 4; ++tj) {
                int col = col0 + wn + tj * 16 + t16;
                float h = fast_tanh(acc[ti][tj][rg] + b1[col]);
                pd += h * bf2f(wrow[tj * 16]);
            }
            pd += __shfl_xor(pd, 1);
            pd += __shfl_xor(pd, 2);
            pd += __shfl_xor(pd, 4);
            pd += __shfl_xor(pd, 8);
            if (t16 == 0)
                partials[(size_t)cb * M_NODES + m] = pd;
        }
    }
}

// ---------------------------------------------------------------------------
__global__ __launch_bounds__(256) void k_reduce(
    const float* __restrict__ partials, const int* __restrict__ r_idx,
    const float* __restrict__ b2, float* __restrict__ out)
{
    int m = blockIdx.x * 256 + threadIdx.x;
    float s = 0.f;
#pragma unroll
    for (int cb = 0; cb < 16; ++cb)
        s += partials[(size_t)cb * M_NODES + m];
    out[m] = s + b2[r_idx[m]];
}

// ---------------------------------------------------------------------------
extern "C" void kernel_launch(void* const* d_in, const int* in_sizes, int n_in,
                              void* d_out, int out_size, void* d_ws, size_t ws_size,
                              hipStream_t stream) {
    const int*   tokens = (const int*)  d_in[0];
    const int*   i_idx  = (const int*)  d_in[1];
    const int*   j_idx  = (const int*)  d_in[2];
    const int*   r_idx  = (const int*)  d_in[3];
    const float* emb    = (const float*)d_in[4];
    const float* Wxh    = (const float*)d_in[5];
    const float* Whh    = (const float*)d_in[6];
    const float* bh     = (const float*)d_in[7];
    const float* h0     = (const float*)d_in[8];
    const float* W1     = (const float*)d_in[9];
    const float* b1     = (const float*)d_in[10];
    const float* W2     = (const float*)d_in[11];
    const float* b2     = (const float*)d_in[12];
    float* out = (float*)d_out;

    // Workspace (~156 MiB). embB (20 MiB) aliases WhhT/W1T/Wt2 (22 MiB):
    // embB dead after k_xw_mfma; those conversions run after it.
    bf16_t* XE   = (bf16_t*)d_ws;                        // [B*L][D]  128 MiB
    bf16_t* WxhT = XE   + (size_t)M_NODES * D_DIM;       // [D][D]      2 MiB
    bf16_t* WhhT = WxhT + (size_t)D_DIM * D_DIM;         // [D][D]      2 MiB
    bf16_t* W1T  = WhhT + (size_t)D_DIM * D_DIM;         // [D][2D]     4 MiB
    bf16_t* Wt2  = W1T  + (size_t)2 * D_DIM * D_DIM;     // [R][D]     16 MiB
    bf16_t* embB = WhhT;                                 // [V][D]     20 MiB (alias)
    bf16_t* h0b  = Wt2  + (size_t)R_RULES * D_DIM;       // [D] (pad 2048)
    int*    bar  = (int*)(h0b + 1536);                   // 4 B inside h0b pad
    float*  par  = (float*)(h0b + 2048);                 // [16][M]     4 MiB

    // Phase 1: emb->bf16, Wxh, h0 (+ zero grid-barrier counter)
    k_cvt_emb<<<V_VOCAB * D_DIM / 2048, 256, 0, stream>>>(emb, embB);
    k_transcvt<<<dim3(D_DIM / 32, D_DIM / 32), dim3(32, 8), 0, stream>>>(Wxh, WxhT, D_DIM, D_DIM);
    k_cvt_h0<<<1, 256, 0, stream>>>(h0, h0b, bar);

    // Phase 2: XE = bf16(embB[tokens] @ Wxh + bh)   (last reader of embB)
    k_xw_mfma<<<4096, 256, 0, stream>>>(tokens, embB, WxhT, bh, XE);

    // Phase 3: remaining weight conversions (overwrite embB region)
    k_transcvt<<<dim3(D_DIM / 32, D_DIM / 32), dim3(32, 8), 0, stream>>>(Whh, WhhT, D_DIM, D_DIM);
    k_transcvt<<<dim3(D_DIM / 32, 2 * D_DIM / 32), dim3(32, 8), 0, stream>>>(W1, W1T, 2 * D_DIM, D_DIM);
    k_transcvt<<<dim3(R_RULES / 32, D_DIM / 32), dim3(32, 8), 0, stream>>>(W2, Wt2, D_DIM, R_RULES);

    // Phase 4: all 64 RNN steps in ONE persistent cooperative kernel
    {
        void* args[] = { (void*)&h0b, (void*)&WhhT, (void*)&XE, (void*)&bar };
        hipLaunchCooperativeKernel((const void*)k_rnn, dim3(NBLK_RNN), dim3(512),
                                   args, 0, stream);
    }

    // Phase 5: MLP + fused rule-dot partials
    k_mlp_mfma<<<4096, 256, 0, stream>>>(
        i_idx, j_idx, XE, W1T, b1, Wt2, r_idx, par);

    // Phase 6: deterministic reduce + b2
    k_reduce<<<M_NODES / 256, 256, 0, stream>>>(par, r_idx, b2, out);
}

// Round 2
// 1254.394 us; speedup vs baseline: 1.6292x; 1.6292x over previous
//
#include <hip/hip_runtime.h>

// V=10000, R=8192, D=1024, B=1024, L=64, M=65536
// R11 = R9 (1280 us) + depth-2 register prefetch in k_mlp/k_xw.
// R10 post-mortem (persistent k_rnn, 2044 us): REVERTED. (a) VGPR=84 proved
// the compiler sank the breg[32] Whh preload back into the loop (restrict
// lets it) -> B reloaded every step; (b) 63 grid barriers w/ agent-release
// fetch_add on one LLC line cost ~14 us each (MfmaUtil 4.2% = pure stall);
// (c) SQ_LDS_BANK_CONFLICT ~3.4e7 appears in BOTH swizzled k_rnn and k_mlp:
// it mostly counts inherent wave64 b128 8-phase serialization, not fixable
// conflicts -> stop chasing it.
// R11 theory: k_mlp (453 us) is gather-LATENCY bound: 417 MB of L2-miss
// 64B-granule XE gathers at 951 GB/s (12% of peak), depth-1 prefetch covers
// ~350 of ~800 cyc. Depth-2 (two k-chunks in flight in regs) gives ~700 cyc
// of cover. Predicted: k_mlp 453->~270 (MfmaUtil 27->42%), k_xw 190->~150.
#define D_DIM   1024
#define L_SEQ   64
#define B_BATCH 1024
#define M_NODES 65536
#define R_RULES 8192
#define V_VOCAB 10000

typedef unsigned short bf16_t;
typedef __attribute__((ext_vector_type(8))) short s8v;   // 8 bf16 (MFMA A/B frag)
typedef __attribute__((ext_vector_type(4))) short s4v;   // 4 bf16
typedef __attribute__((ext_vector_type(4))) float f4v;   // MFMA C/D frag

static __device__ __forceinline__ float bf2f(unsigned short u) {
    union { unsigned int i; float f; } v; v.i = ((unsigned int)u) << 16; return v.f;
}
static __device__ __forceinline__ unsigned short f2bf(float f) {  // RNE
    union { float f; unsigned int i; } v; v.f = f;
    return (unsigned short)((v.i + 0x7FFFu + ((v.i >> 16) & 1u)) >> 16);
}
static __device__ __forceinline__ float fast_tanh(float x) {
    float xc = fminf(fmaxf(x, -15.f), 15.f);
    float t  = __expf(2.f * xc);
    return (t - 1.f) * __builtin_amdgcn_rcpf(t + 1.f);
}

static __device__ __forceinline__ f4v mfma16(s8v a, s8v b, f4v c) {
    return __builtin_amdgcn_mfma_f32_16x16x32_bf16(a, b, c, 0, 0, 0);
}

// ---------------------------------------------------------------------------
__global__ __launch_bounds__(256) void k_cvt_emb(
    const float* __restrict__ emb, bf16_t* __restrict__ embB)
{
    size_t i = ((size_t)blockIdx.x * 256 + threadIdx.x) * 8;
    f4v x0 = *(const f4v*)&emb[i];
    f4v x1 = *(const f4v*)&emb[i + 4];
    s8v o;
    o[0] = (short)f2bf(x0.x); o[1] = (short)f2bf(x0.y);
    o[2] = (short)f2bf(x0.z); o[3] = (short)f2bf(x0.w);
    o[4] = (short)f2bf(x1.x); o[5] = (short)f2bf(x1.y);
    o[6] = (short)f2bf(x1.z); o[7] = (short)f2bf(x1.w);
    *(s8v*)&embB[i] = o;
}

__global__ __launch_bounds__(256) void k_transcvt(
    const float* __restrict__ src, bf16_t* __restrict__ dst, int K, int N)
{
    __shared__ float s[32][33];
    int n0 = blockIdx.x * 32, k0 = blockIdx.y * 32;
    int tx = threadIdx.x, ty = threadIdx.y;  // (32,8)
#pragma unroll
    for (int i = 0; i < 4; ++i)
        s[ty + i * 8][tx] = src[(size_t)(k0 + ty + i * 8) * N + n0 + tx];
    __syncthreads();
#pragma unroll
    for (int i = 0; i < 4; ++i)
        dst[(size_t)(n0 + ty + i * 8) * K + k0 + tx] = f2bf(s[tx][ty + i * 8]);
}

__global__ __launch_bounds__(256) void k_cvt_h0(
    const float* __restrict__ h0, bf16_t* __restrict__ h0b)
{
    for (int u = threadIdx.x; u < D_DIM; u += 256) h0b[u] = f2bf(h0[u]);
}

// ---------------------------------------------------------------------------
// k_xw_mfma: XE[n,:] = bf16(embB[tokens[n],:] @ Wxh + bh)
// 128x128 tile, BK=32, manual staging + depth-2 VGPR prefetch, XCD swizzle.
// ---------------------------------------------------------------------------
__global__ __launch_bounds__(256) void k_xw_mfma(
    const int* __restrict__ tokens, const bf16_t* __restrict__ embB,
    const bf16_t* __restrict__ WxhT, const float* __restrict__ bh,
    bf16_t* __restrict__ XE)
{
    __shared__ bf16_t As[128 * 32];            // 8 KB
    __shared__ bf16_t Bs[128 * 32];            // 8 KB
    __shared__ float  epi[4][16][68];          // 17.4 KB (per-wave private)

    const int bi  = blockIdx.x;
    const int xcd = bi & 7, j = bi >> 3;
    const int row0 = ((xcd << 6) + (j >> 3)) * 128;   // rowTile in [0,512)
    const int col0 = (j & 7) * 128;                   // colTile in [0,8)

    const int tid = threadIdx.x;
    const int w = tid >> 6, l = tid & 63;
    const int q = l >> 4, t16 = l & 15;
    const int wm = (w >> 1) * 64, wn = (w & 1) * 64;

    const bf16_t* arow[2];
#pragma unroll
    for (int r = 0; r < 2; ++r)
        arow[r] = embB + (size_t)tokens[row0 + (tid >> 2) + r * 64] * D_DIM + ((tid & 3) << 3);
    const bf16_t* brow[2];
#pragma unroll
    for (int r = 0; r < 2; ++r)
        brow[r] = WxhT + (size_t)(col0 + (tid >> 2) + r * 64) * D_DIM + ((tid & 3) << 3);

    f4v acc[4][4];
#pragma unroll
    for (int i = 0; i < 4; ++i)
#pragma unroll
        for (int jj = 0; jj < 4; ++jj) acc[i][jj] = (f4v)0.f;

    // depth-2 prefetch: chunks 0 and 1 in flight
    s8v a0_0 = *(const s8v*)(arow[0]);
    s8v a1_0 = *(const s8v*)(arow[1]);
    s8v b0_0 = *(const s8v*)(brow[0]);
    s8v b1_0 = *(const s8v*)(brow[1]);
    s8v a0_1 = *(const s8v*)(arow[0] + 32);
    s8v a1_1 = *(const s8v*)(arow[1] + 32);
    s8v b0_1 = *(const s8v*)(brow[0] + 32);
    s8v b1_1 = *(const s8v*)(brow[1] + 32);

    const int rr = tid >> 2, cc = (tid & 3) << 3;

#define XW_COMPUTE()                                                          \
    {                                                                         \
        s8v af[4], bfr[4];                                                    \
        _Pragma("unroll")                                                     \
        for (int ti = 0; ti < 4; ++ti)                                        \
            af[ti] = *(const s8v*)&As[(wm + ti * 16 + t16) * 32 + q * 8];     \
        _Pragma("unroll")                                                     \
        for (int tj = 0; tj < 4; ++tj)                                        \
            bfr[tj] = *(const s8v*)&Bs[(wn + tj * 16 + t16) * 32 + q * 8];    \
        _Pragma("unroll")                                                     \
        for (int ti = 0; ti < 4; ++ti)                                        \
            _Pragma("unroll")                                                 \
            for (int tj = 0; tj < 4; ++tj)                                    \
                acc[ti][tj] = mfma16(af[ti], bfr[tj], acc[ti][tj]);           \
    }

    for (int c = 0; c < D_DIM / 32; c += 2) {
        // even sub-iter: consume buffer 0, refill with chunk c+2
        __syncthreads();
        *(s8v*)&As[rr * 32 + cc]        = a0_0;
        *(s8v*)&As[(rr + 64) * 32 + cc] = a1_0;
        *(s8v*)&Bs[rr * 32 + cc]        = b0_0;
        *(s8v*)&Bs[(rr + 64) * 32 + cc] = b1_0;
        int kn = (c + 2) * 32;
        if (kn < D_DIM) {
            a0_0 = *(const s8v*)(arow[0] + kn);
            a1_0 = *(const s8v*)(arow[1] + kn);
            b0_0 = *(const s8v*)(brow[0] + kn);
            b1_0 = *(const s8v*)(brow[1] + kn);
        }
        __syncthreads();
        XW_COMPUTE();
        // odd sub-iter: consume buffer 1, refill with chunk c+3
        __syncthreads();
        *(s8v*)&As[rr * 32 + cc]        = a0_1;
        *(s8v*)&As[(rr + 64) * 32 + cc] = a1_1;
        *(s8v*)&Bs[rr * 32 + cc]        = b0_1;
        *(s8v*)&Bs[(rr + 64) * 32 + cc] = b1_1;
        kn = (c + 3) * 32;
        if (kn < D_DIM) {
            a0_1 = *(const s8v*)(arow[0] + kn);
            a1_1 = *(const s8v*)(arow[1] + kn);
            b0_1 = *(const s8v*)(brow[0] + kn);
            b1_1 = *(const s8v*)(brow[1] + kn);
        }
        __syncthreads();
        XW_COMPUTE();
    }
#undef XW_COMPUTE

    // barrier-free per-wave epilogue (epi[w] wave-private)
    const int lr = l >> 2, c16 = (l & 3) * 16;
    f4v bias[4];
#pragma unroll
    for (int u = 0; u < 4; ++u)
        bias[u] = *(const f4v*)&bh[col0 + wn + c16 + u * 4];
#pragma unroll
    for (int ti = 0; ti < 4; ++ti) {
#pragma unroll
        for (int tj = 0; tj < 4; ++tj)
#pragma unroll
            for (int rg = 0; rg < 4; ++rg)
                epi[w][q * 4 + rg][tj * 16 + t16] = acc[ti][tj][rg];
        s8v o0, o1;
#pragma unroll
        for (int u = 0; u < 8; ++u) {
            o0[u] = (short)f2bf(epi[w][lr][c16 + u]     + bias[u >> 2][u & 3]);
            o1[u] = (short)f2bf(epi[w][lr][c16 + 8 + u] + bias[2 + (u >> 2)][u & 3]);
        }
        size_t orow = (size_t)(row0 + wm + ti * 16 + lr) * D_DIM + col0 + wn + c16;
        *(s8v*)&XE[orow]     = o0;
        *(s8v*)&XE[orow + 8] = o1;
    }
}

// ---------------------------------------------------------------------------
// k_step_mfma (x64): y = tanh(XE[b*L+t,:] + h_prev[b,:] @ Whh); XE[..] = bf16(y)
// 64x64 tile, 512 threads (8 waves = 2/SIMD), SW-prefetch, fast_tanh.
// (R7 version verbatim — proven 9.4 us/step; R10's persistent variant was 2x
// slower end-to-end.)
// ---------------------------------------------------------------------------
__global__ __launch_bounds__(512) void k_step_mfma(
    const bf16_t* __restrict__ Abase, int strideRow,
    const bf16_t* __restrict__ WhhT, bf16_t* __restrict__ XE, int t)
{
    __shared__ bf16_t As[64 * 32];             // 4 KB
    __shared__ bf16_t Bs[64 * 32];             // 4 KB
    __shared__ float  epi[8][16][20];          // 10.2 KB (per-wave private)

    const int tid = threadIdx.x;
    const int w = tid >> 6, l = tid & 63;
    const int q = l >> 4, t16 = l & 15;
    const int wr = w >> 2, wc = w & 3;
    const int row0 = blockIdx.x * 64, col0 = blockIdx.y * 64;

    const bf16_t* asrc = Abase + (size_t)(row0 + (tid >> 3)) * strideRow + ((tid & 7) << 2);
    const bf16_t* bsrc = WhhT + (size_t)(col0 + (tid >> 3)) * D_DIM + ((tid & 7) << 2);

    f4v acc[2];
    acc[0] = (f4v)0.f; acc[1] = (f4v)0.f;

    s4v rA = *(const s4v*)(asrc);
    s4v rB = *(const s4v*)(bsrc);

    const int srow = tid >> 3, scol = (tid & 7) << 2;
    for (int k0 = 0; k0 < D_DIM; k0 += 32) {
        __syncthreads();
        *(s4v*)&As[srow * 32 + scol] = rA;
        *(s4v*)&Bs[srow * 32 + scol] = rB;
        int kn = k0 + 32;
        if (kn < D_DIM) {
            rA = *(const s4v*)(asrc + kn);
            rB = *(const s4v*)(bsrc + kn);
        }
        __syncthreads();
        s8v af[2], bfr;
#pragma unroll
        for (int ti = 0; ti < 2; ++ti)
            af[ti] = *(const s8v*)&As[(wr * 32 + ti * 16 + t16) * 32 + q * 8];
        bfr = *(const s8v*)&Bs[(wc * 16 + t16) * 32 + q * 8];
#pragma unroll
        for (int ti = 0; ti < 2; ++ti)
            acc[ti] = mfma16(af[ti], bfr, acc[ti]);
    }

    // per-wave epilogue, no barriers
    const int lr = l >> 2, c4 = (l & 3) * 4;
#pragma unroll
    for (int ti = 0; ti < 2; ++ti) {
#pragma unroll
        for (int rg = 0; rg < 4; ++rg)
            epi[w][q * 4 + rg][t16] = acc[ti][rg];
        f4v v = *(const f4v*)&epi[w][lr][c4];
        int b = row0 + wr * 32 + ti * 16 + lr;
        size_t xi = ((size_t)b * L_SEQ + t) * D_DIM + col0 + wc * 16 + c4;
        s4v x = *(const s4v*)&XE[xi];
        s4v o;
#pragma unroll
        for (int u = 0; u < 4; ++u)
            o[u] = (short)f2bf(fast_tanh(bf2f((unsigned short)x[u]) + v[u]));
        *(s4v*)&XE[xi] = o;
    }
}

// ---------------------------------------------------------------------------
// k_mlp_mfma: h = tanh(concat(XE[i],XE[j]) @ W1 + b1) fused with rule-dot.
// 128x128 tile, K=2048, manual staging + depth-2 prefetch, XCD swizzle.
// ---------------------------------------------------------------------------
__global__ __launch_bounds__(256) void k_mlp_mfma(
    const int* __restrict__ i_idx, const int* __restrict__ j_idx,
    const bf16_t* __restrict__ XE, const bf16_t* __restrict__ W1T,
    const float* __restrict__ b1, const bf16_t* __restrict__ Wt2,
    const int* __restrict__ r_idx, float* __restrict__ partials)
{
    __shared__ bf16_t As[128 * 32];            // 8 KB
    __shared__ bf16_t Bs[128 * 32];            // 8 KB

    const int bi  = blockIdx.x;
    const int xcd = bi & 7, j = bi >> 3;
    const int rowTile = (xcd << 6) + (j >> 3);        // [0,512)
    const int colTile = j & 7;                        // [0,8)
    const int row0 = rowTile * 128, col0 = colTile * 128;

    const int tid = threadIdx.x;
    const int w = tid >> 6, l = tid & 63;
    const int q = l >> 4, t16 = l & 15;
    const int wm = (w >> 1) * 64, wn = (w & 1) * 64;

    const bf16_t* pi[2]; const bf16_t* pj[2];
#pragma unroll
    for (int r = 0; r < 2; ++r) {
        int m = row0 + (tid >> 2) + r * 64;
        pi[r] = XE + (size_t)i_idx[m] * D_DIM + ((tid & 3) << 3);
        pj[r] = XE + (size_t)j_idx[m] * D_DIM - D_DIM + ((tid & 3) << 3);  // k in [1024,2048)
    }
    const bf16_t* brow[2];
#pragma unroll
    for (int r = 0; r < 2; ++r)
        brow[r] = W1T + (size_t)(col0 + (tid >> 2) + r * 64) * (2 * D_DIM) + ((tid & 3) << 3);

    f4v acc[4][4];
#pragma unroll
    for (int i = 0; i < 4; ++i)
#pragma unroll
        for (int jj = 0; jj < 4; ++jj) acc[i][jj] = (f4v)0.f;

    // depth-2 prefetch: chunks 0 and 1 in flight
    s8v a0_0 = *(const s8v*)(pi[0]);
    s8v a1_0 = *(const s8v*)(pi[1]);
    s8v b0_0 = *(const s8v*)(brow[0]);
    s8v b1_0 = *(const s8v*)(brow[1]);
    s8v a0_1 = *(const s8v*)(pi[0] + 32);
    s8v a1_1 = *(const s8v*)(pi[1] + 32);
    s8v b0_1 = *(const s8v*)(brow[0] + 32);
    s8v b1_1 = *(const s8v*)(brow[1] + 32);

    const int rr = tid >> 2, cc = (tid & 3) << 3;

#define MLP_COMPUTE()                                                         \
    {                                                                         \
        s8v af[4], bfr[4];                                                    \
        _Pragma("unroll")                                                     \
        for (int ti = 0; ti < 4; ++ti)                                        \
            af[ti] = *(const s8v*)&As[(wm + ti * 16 + t16) * 32 + q * 8];     \
        _Pragma("unroll")                                                     \
        for (int tj = 0; tj < 4; ++tj)                                        \
            bfr[tj] = *(const s8v*)&Bs[(wn + tj * 16 + t16) * 32 + q * 8];    \
        _Pragma("unroll")                                                     \
        for (int ti = 0; ti < 4; ++ti)                                        \
            _Pragma("unroll")                                                 \
            for (int tj = 0; tj < 4; ++tj)                                    \
                acc[ti][tj] = mfma16(af[ti], bfr[tj], acc[ti][tj]);           \
    }

    for (int c = 0; c < 2 * D_DIM / 32; c += 2) {
        // even sub-iter: consume buffer 0, refill with chunk c+2
        __syncthreads();
        *(s8v*)&As[rr * 32 + cc]        = a0_0;
        *(s8v*)&As[(rr + 64) * 32 + cc] = a1_0;
        *(s8v*)&Bs[rr * 32 + cc]        = b0_0;
        *(s8v*)&Bs[(rr + 64) * 32 + cc] = b1_0;
        int kn = (c + 2) * 32;
        if (kn < 2 * D_DIM) {
            a0_0 = *(const s8v*)(((kn < D_DIM) ? pi[0] : pj[0]) + kn);
            a1_0 = *(const s8v*)(((kn < D_DIM) ? pi[1] : pj[1]) + kn);
            b0_0 = *(const s8v*)(brow[0] + kn);
            b1_0 = *(const s8v*)(brow[1] + kn);
        }
        __syncthreads();
        MLP_COMPUTE();
        // odd sub-iter: consume buffer 1, refill with chunk c+3
        __syncthreads();
        *(s8v*)&As[rr * 32 + cc]        = a0_1;
        *(s8v*)&As[(rr + 64) * 32 + cc] = a1_1;
        *(s8v*)&Bs[rr * 32 + cc]        = b0_1;
        *(s8v*)&Bs[(rr + 64) * 32 + cc] = b1_1;
        kn = (c + 3) * 32;
        if (kn < 2 * D_DIM) {
            a0_1 = *(const s8v*)(((kn < D_DIM) ? pi[0] : pj[0]) + kn);
            a1_1 = *(const s8v*)(((kn < D_DIM) ? pi[1] : pj[1]) + kn);
            b0_1 = *(const s8v*)(brow[0] + kn);
            b1_1 = *(const s8v*)(brow[1] + kn);
        }
        __syncthreads();
        MLP_COMPUTE();
    }
#undef MLP_COMPUTE

    // fused epilogue in C-layout: fast_tanh, dot with gathered rule row, 16-lane reduce
    const int cb = colTile * 2 + (w & 1);
#pragma unroll
    for (int ti = 0; ti < 4; ++ti) {
#pragma unroll
        for (int rg = 0; rg < 4; ++rg) {
            int m = row0 + wm + ti * 16 + q * 4 + rg;
            int r = r_idx[m];
            const bf16_t* wrow = Wt2 + (size_t)r * D_DIM + col0 + wn + t16;
            float pd = 0.f;
#pragma unroll
            for (int tj = 0; tj < 4; ++tj) {
                int col = col0 + wn + tj * 16 + t16;
                float h = fast_tanh(acc[ti][tj][rg] + b1[col]);
                pd += h * bf2f(wrow[tj * 16]);
            }
            pd += __shfl_xor(pd, 1);
            pd += __shfl_xor(pd, 2);
            pd += __shfl_xor(pd, 4);
            pd += __shfl_xor(pd, 8);
            if (t16 == 0)
                partials[(size_t)cb * M_NODES + m] = pd;
        }
    }
}

// ---------------------------------------------------------------------------
__global__ __launch_bounds__(256) void k_reduce(
    const float* __restrict__ partials, const int* __restrict__ r_idx,
    const float* __restrict__ b2, float* __restrict__ out)
{
    int m = blockIdx.x * 256 + threadIdx.x;
    float s = 0.f;
#pragma unroll
    for (int cb = 0; cb < 16; ++cb)
        s += partials[(size_t)cb * M_NODES + m];
    out[m] = s + b2[r_idx[m]];
}

// ---------------------------------------------------------------------------
extern "C" void kernel_launch(void* const* d_in, const int* in_sizes, int n_in,
                              void* d_out, int out_size, void* d_ws, size_t ws_size,
                              hipStream_t stream) {
    const int*   tokens = (const int*)  d_in[0];
    const int*   i_idx  = (const int*)  d_in[1];
    const int*   j_idx  = (const int*)  d_in[2];
    const int*   r_idx  = (const int*)  d_in[3];
    const float* emb    = (const float*)d_in[4];
    const float* Wxh    = (const float*)d_in[5];
    const float* Whh    = (const float*)d_in[6];
    const float* bh     = (const float*)d_in[7];
    const float* h0     = (const float*)d_in[8];
    const float* W1     = (const float*)d_in[9];
    const float* b1     = (const float*)d_in[10];
    const float* W2     = (const float*)d_in[11];
    const float* b2     = (const float*)d_in[12];
    float* out = (float*)d_out;

    // Workspace (~156 MiB). embB (20 MiB) aliases WhhT/W1T/Wt2 (22 MiB):
    // embB dead after k_xw_mfma; those conversions run after it.
    bf16_t* XE   = (bf16_t*)d_ws;                        // [B*L][D]  128 MiB
    bf16_t* WxhT = XE   + (size_t)M_NODES * D_DIM;       // [D][D]      2 MiB
    bf16_t* WhhT = WxhT + (size_t)D_DIM * D_DIM;         // [D][D]      2 MiB
    bf16_t* W1T  = WhhT + (size_t)D_DIM * D_DIM;         // [D][2D]     4 MiB
    bf16_t* Wt2  = W1T  + (size_t)2 * D_DIM * D_DIM;     // [R][D]     16 MiB
    bf16_t* embB = WhhT;                                 // [V][D]     20 MiB (alias)
    bf16_t* h0b  = Wt2  + (size_t)R_RULES * D_DIM;       // [D] (pad 2048)
    float*  par  = (float*)(h0b + 2048);                 // [16][M]     4 MiB

    // Phase 1: emb->bf16, Wxh, h0
    k_cvt_emb<<<V_VOCAB * D_DIM / 2048, 256, 0, stream>>>(emb, embB);
    k_transcvt<<<dim3(D_DIM / 32, D_DIM / 32), dim3(32, 8), 0, stream>>>(Wxh, WxhT, D_DIM, D_DIM);
    k_cvt_h0<<<1, 256, 0, stream>>>(h0, h0b);

    // Phase 2: XE = bf16(embB[tokens] @ Wxh + bh)   (last reader of embB)
    k_xw_mfma<<<4096, 256, 0, stream>>>(tokens, embB, WxhT, bh, XE);

    // Phase 3: remaining weight conversions (overwrite embB region)
    k_transcvt<<<dim3(D_DIM / 32, D_DIM / 32), dim3(32, 8), 0, stream>>>(Whh, WhhT, D_DIM, D_DIM);
    k_transcvt<<<dim3(D_DIM / 32, 2 * D_DIM / 32), dim3(32, 8), 0, stream>>>(W1, W1T, 2 * D_DIM, D_DIM);
    k_transcvt<<<dim3(R_RULES / 32, D_DIM / 32), dim3(32, 8), 0, stream>>>(W2, Wt2, D_DIM, R_RULES);

    // Phase 4: 64 sequential RNN steps (in-place on XE)
    for (int t = 0; t < L_SEQ; ++t) {
        const bf16_t* Abase = (t == 0) ? h0b : (XE + (size_t)(t - 1) * D_DIM);
        int strideRow       = (t == 0) ? 0   : L_SEQ * D_DIM;
        k_step_mfma<<<dim3(B_BATCH / 64, D_DIM / 64), 512, 0, stream>>>(
            Abase, strideRow, WhhT, XE, t);
    }

    // Phase 5: MLP + fused rule-dot partials
    k_mlp_mfma<<<4096, 256, 0, stream>>>(
        i_idx, j_idx, XE, W1T, b1, Wt2, r_idx, par);

    // Phase 6: deterministic reduce + b2
    k_reduce<<<M_NODES / 256, 256, 0, stream>>>(par, r_idx, b2, out);
}

// Round 3
// 1069.228 us; speedup vs baseline: 1.9113x; 1.1732x over previous
//
#include <hip/hip_runtime.h>

// V=10000, R=8192, D=1024, B=1024, L=64, M=65536
// R12 = R11 (1254 us) with the LDS bank-conflict + barrier-cadence fix:
// the old [row][32] tiles put all 16 t16-lanes of each ds_read_b128 on 2 of
// 8 bank-quads (row stride 64B) -> ~4x serialized frag reads = the 3.4e7
// SQ_LDS_BANK_CONFLICT I wrongly called "inherent" in R10/R11 notes.
// All three MFMA kernels now use: BK=64 (half the barriers, compute phase
// ~1240cyc >= gather latency -> depth-1 prefetch), [row][64] LDS tiles with
// 16B-slot XOR swizzle (slot ^= row&7, same involution on write+read),
// even 8-lanes-per-quad on every b128 = conflict-free optimum.
// k_step rebuilt: 64x64 tile, 256 thr, 4 waves as 2x2 quadrants of 32x32
// (4 MFMA per wave-subk vs 2 -> MFMA:LDS ratio 1.0), 33 barriers/step
// (was 65), 16B stores. Depth-2 prefetch (R11, +6% only) reverted.
#define D_DIM   1024
#define L_SEQ   64
#define B_BATCH 1024
#define M_NODES 65536
#define R_RULES 8192
#define V_VOCAB 10000

typedef unsigned short bf16_t;
typedef __attribute__((ext_vector_type(8))) short s8v;   // 8 bf16 (MFMA A/B frag)
typedef __attribute__((ext_vector_type(4))) short s4v;   // 4 bf16
typedef __attribute__((ext_vector_type(4))) float f4v;   // MFMA C/D frag

static __device__ __forceinline__ float bf2f(unsigned short u) {
    union { unsigned int i; float f; } v; v.i = ((unsigned int)u) << 16; return v.f;
}
static __device__ __forceinline__ unsigned short f2bf(float f) {  // RNE
    union { float f; unsigned int i; } v; v.f = f;
    return (unsigned short)((v.i + 0x7FFFu + ((v.i >> 16) & 1u)) >> 16);
}
static __device__ __forceinline__ float fast_tanh(float x) {
    float xc = fminf(fmaxf(x, -15.f), 15.f);
    float t  = __expf(2.f * xc);
    return (t - 1.f) * __builtin_amdgcn_rcpf(t + 1.f);
}

static __device__ __forceinline__ f4v mfma16(s8v a, s8v b, f4v c) {
    return __builtin_amdgcn_mfma_f32_16x16x32_bf16(a, b, c, 0, 0, 0);
}

// ---------------------------------------------------------------------------
__global__ __launch_bounds__(256) void k_cvt_emb(
    const float* __restrict__ emb, bf16_t* __restrict__ embB)
{
    size_t i = ((size_t)blockIdx.x * 256 + threadIdx.x) * 8;
    f4v x0 = *(const f4v*)&emb[i];
    f4v x1 = *(const f4v*)&emb[i + 4];
    s8v o;
    o[0] = (short)f2bf(x0.x); o[1] = (short)f2bf(x0.y);
    o[2] = (short)f2bf(x0.z); o[3] = (short)f2bf(x0.w);
    o[4] = (short)f2bf(x1.x); o[5] = (short)f2bf(x1.y);
    o[6] = (short)f2bf(x1.z); o[7] = (short)f2bf(x1.w);
    *(s8v*)&embB[i] = o;
}

__global__ __launch_bounds__(256) void k_transcvt(
    const float* __restrict__ src, bf16_t* __restrict__ dst, int K, int N)
{
    __shared__ float s[32][33];
    int n0 = blockIdx.x * 32, k0 = blockIdx.y * 32;
    int tx = threadIdx.x, ty = threadIdx.y;  // (32,8)
#pragma unroll
    for (int i = 0; i < 4; ++i)
        s[ty + i * 8][tx] = src[(size_t)(k0 + ty + i * 8) * N + n0 + tx];
    __syncthreads();
#pragma unroll
    for (int i = 0; i < 4; ++i)
        dst[(size_t)(n0 + ty + i * 8) * K + k0 + tx] = f2bf(s[tx][ty + i * 8]);
}

__global__ __launch_bounds__(256) void k_cvt_h0(
    const float* __restrict__ h0, bf16_t* __restrict__ h0b)
{
    for (int u = threadIdx.x; u < D_DIM; u += 256) h0b[u] = f2bf(h0[u]);
}

// ---------------------------------------------------------------------------
// k_xw_mfma: XE[n,:] = bf16(embB[tokens[n],:] @ Wxh + bh)
// 128x128 tile, BK=64, swizzled LDS, depth-1 VGPR prefetch, XCD swizzle.
// ---------------------------------------------------------------------------
__global__ __launch_bounds__(256) void k_xw_mfma(
    const int* __restrict__ tokens, const bf16_t* __restrict__ embB,
    const bf16_t* __restrict__ WxhT, const float* __restrict__ bh,
    bf16_t* __restrict__ XE)
{
    __shared__ bf16_t As[128 * 64];            // 16 KB (swizzled 16B slots)
    __shared__ bf16_t Bs[128 * 64];            // 16 KB
    __shared__ float  epi[4][16][68];          // 17.4 KB (per-wave private)

    const int bi  = blockIdx.x;
    const int xcd = bi & 7, j = bi >> 3;
    const int row0 = ((xcd << 6) + (j >> 3)) * 128;   // rowTile in [0,512)
    const int col0 = (j & 7) * 128;                   // colTile in [0,8)

    const int tid = threadIdx.x;
    const int w = tid >> 6, l = tid & 63;
    const int q = l >> 4, t16 = l & 15;
    const int wm = (w >> 1) * 64, wn = (w & 1) * 64;

    const int rr = tid >> 2, c0 = tid & 3;            // staging row / base slot
    const int sw0 = ((c0       ^ (rr & 7)) << 3);     // swizzled slot offsets
    const int sw1 = (((c0 + 4) ^ (rr & 7)) << 3);     // ((rr+64)&7)==(rr&7)

    const bf16_t* arow[2];
#pragma unroll
    for (int r = 0; r < 2; ++r)
        arow[r] = embB + (size_t)tokens[row0 + rr + r * 64] * D_DIM + c0 * 8;
    const bf16_t* brow[2];
#pragma unroll
    for (int r = 0; r < 2; ++r)
        brow[r] = WxhT + (size_t)(col0 + rr + r * 64) * D_DIM + c0 * 8;

    f4v acc[4][4];
#pragma unroll
    for (int i = 0; i < 4; ++i)
#pragma unroll
        for (int jj = 0; jj < 4; ++jj) acc[i][jj] = (f4v)0.f;

    // prefetch chunk 0 (8 x 16B)
    s8v a00 = *(const s8v*)(arow[0]);
    s8v a01 = *(const s8v*)(arow[0] + 32);
    s8v a10 = *(const s8v*)(arow[1]);
    s8v a11 = *(const s8v*)(arow[1] + 32);
    s8v b00 = *(const s8v*)(brow[0]);
    s8v b01 = *(const s8v*)(brow[0] + 32);
    s8v b10 = *(const s8v*)(brow[1]);
    s8v b11 = *(const s8v*)(brow[1] + 32);

    const int r7 = t16 & 7;
    for (int k0 = 0; k0 < D_DIM; k0 += 64) {
        __syncthreads();                       // prev iter frag reads done
        *(s8v*)&As[rr * 64 + sw0]        = a00;
        *(s8v*)&As[rr * 64 + sw1]        = a01;
        *(s8v*)&As[(rr + 64) * 64 + sw0] = a10;
        *(s8v*)&As[(rr + 64) * 64 + sw1] = a11;
        *(s8v*)&Bs[rr * 64 + sw0]        = b00;
        *(s8v*)&Bs[rr * 64 + sw1]        = b01;
        *(s8v*)&Bs[(rr + 64) * 64 + sw0] = b10;
        *(s8v*)&Bs[(rr + 64) * 64 + sw1] = b11;
        int kn = k0 + 64;
        if (kn < D_DIM) {                      // issue next loads early
            a00 = *(const s8v*)(arow[0] + kn);
            a01 = *(const s8v*)(arow[0] + kn + 32);
            a10 = *(const s8v*)(arow[1] + kn);
            a11 = *(const s8v*)(arow[1] + kn + 32);
            b00 = *(const s8v*)(brow[0] + kn);
            b01 = *(const s8v*)(brow[0] + kn + 32);
            b10 = *(const s8v*)(brow[1] + kn);
            b11 = *(const s8v*)(brow[1] + kn + 32);
        }
        __syncthreads();
#pragma unroll
        for (int sub = 0; sub < 2; ++sub) {
            const int rsl = (((sub * 4 + q) ^ r7) << 3);
            s8v af[4], bfr[4];
#pragma unroll
            for (int ti = 0; ti < 4; ++ti)
                af[ti] = *(const s8v*)&As[(wm + ti * 16 + t16) * 64 + rsl];
#pragma unroll
            for (int tj = 0; tj < 4; ++tj)
                bfr[tj] = *(const s8v*)&Bs[(wn + tj * 16 + t16) * 64 + rsl];
#pragma unroll
            for (int ti = 0; ti < 4; ++ti)
#pragma unroll
                for (int tj = 0; tj < 4; ++tj)
                    acc[ti][tj] = mfma16(af[ti], bfr[tj], acc[ti][tj]);
        }
    }

    // barrier-free per-wave epilogue (epi[w] wave-private)
    const int lr = l >> 2, c16 = (l & 3) * 16;
    f4v bias[4];
#pragma unroll
    for (int u = 0; u < 4; ++u)
        bias[u] = *(const f4v*)&bh[col0 + wn + c16 + u * 4];
#pragma unroll
    for (int ti = 0; ti < 4; ++ti) {
#pragma unroll
        for (int tj = 0; tj < 4; ++tj)
#pragma unroll
            for (int rg = 0; rg < 4; ++rg)
                epi[w][q * 4 + rg][tj * 16 + t16] = acc[ti][tj][rg];
        s8v o0, o1;
#pragma unroll
        for (int u = 0; u < 8; ++u) {
            o0[u] = (short)f2bf(epi[w][lr][c16 + u]     + bias[u >> 2][u & 3]);
            o1[u] = (short)f2bf(epi[w][lr][c16 + 8 + u] + bias[2 + (u >> 2)][u & 3]);
        }
        size_t orow = (size_t)(row0 + wm + ti * 16 + lr) * D_DIM + col0 + wn + c16;
        *(s8v*)&XE[orow]     = o0;
        *(s8v*)&XE[orow + 8] = o1;
    }
}

// ---------------------------------------------------------------------------
// k_step_mfma (x64): y = tanh(XE[b*L+t,:] + h_prev[b,:] @ Whh); XE[..] = bf16(y)
// 64x64 tile, 256 threads, 4 waves as 2x2 quadrants of 32x32, BK=64,
// swizzled LDS, depth-1 prefetch. 33 barriers/step (was 65).
// ---------------------------------------------------------------------------
__global__ __launch_bounds__(256) void k_step_mfma(
    const bf16_t* __restrict__ Abase, int strideRow,
    const bf16_t* __restrict__ WhhT, bf16_t* __restrict__ XE, int t)
{
    __shared__ bf16_t As[64 * 64];             // 8 KB
    __shared__ bf16_t Bs[64 * 64];             // 8 KB
    __shared__ float  epi[4][16][36];          // 9.2 KB (per-wave private)

    const int tid = threadIdx.x;
    const int w = tid >> 6, l = tid & 63;
    const int q = l >> 4, t16 = l & 15;
    const int wr = w >> 1, wc = w & 1;         // 2x2 quadrants of 32x32
    const int row0 = blockIdx.x * 64, col0 = blockIdx.y * 64;

    const int rr = tid >> 2, c0 = tid & 3;
    const int sw0 = ((c0       ^ (rr & 7)) << 3);
    const int sw1 = (((c0 + 4) ^ (rr & 7)) << 3);

    const bf16_t* asrc = Abase + (size_t)(row0 + rr) * strideRow + c0 * 8;
    const bf16_t* bsrc = WhhT + (size_t)(col0 + rr) * D_DIM + c0 * 8;

    f4v acc[2][2];
#pragma unroll
    for (int i = 0; i < 2; ++i)
#pragma unroll
        for (int jj = 0; jj < 2; ++jj) acc[i][jj] = (f4v)0.f;

    s8v a0 = *(const s8v*)(asrc);
    s8v a1 = *(const s8v*)(asrc + 32);
    s8v b0 = *(const s8v*)(bsrc);
    s8v b1 = *(const s8v*)(bsrc + 32);

    const int r7 = t16 & 7;
    for (int k0 = 0; k0 < D_DIM; k0 += 64) {
        __syncthreads();
        *(s8v*)&As[rr * 64 + sw0] = a0;
        *(s8v*)&As[rr * 64 + sw1] = a1;
        *(s8v*)&Bs[rr * 64 + sw0] = b0;
        *(s8v*)&Bs[rr * 64 + sw1] = b1;
        int kn = k0 + 64;
        if (kn < D_DIM) {
            a0 = *(const s8v*)(asrc + kn);
            a1 = *(const s8v*)(asrc + kn + 32);
            b0 = *(const s8v*)(bsrc + kn);
            b1 = *(const s8v*)(bsrc + kn + 32);
        }
        __syncthreads();
#pragma unroll
        for (int sub = 0; sub < 2; ++sub) {
            const int rsl = (((sub * 4 + q) ^ r7) << 3);
            s8v af[2], bfr[2];
#pragma unroll
            for (int ti = 0; ti < 2; ++ti)
                af[ti] = *(const s8v*)&As[(wr * 32 + ti * 16 + t16) * 64 + rsl];
#pragma unroll
            for (int tj = 0; tj < 2; ++tj)
                bfr[tj] = *(const s8v*)&Bs[(wc * 32 + tj * 16 + t16) * 64 + rsl];
#pragma unroll
            for (int ti = 0; ti < 2; ++ti)
#pragma unroll
                for (int tj = 0; tj < 2; ++tj)
                    acc[ti][tj] = mfma16(af[ti], bfr[tj], acc[ti][tj]);
        }
    }

    // per-wave epilogue, no barriers: transpose 16x32 per ti, add u_t, tanh
    const int lr = l >> 2, cg = l & 3;
#pragma unroll
    for (int ti = 0; ti < 2; ++ti) {
#pragma unroll
        for (int tj = 0; tj < 2; ++tj)
#pragma unroll
            for (int rg = 0; rg < 4; ++rg)
                epi[w][q * 4 + rg][tj * 16 + t16] = acc[ti][tj][rg];
        f4v v0 = *(const f4v*)&epi[w][lr][cg * 8];
        f4v v1 = *(const f4v*)&epi[w][lr][cg * 8 + 4];
        int b = row0 + wr * 32 + ti * 16 + lr;
        size_t xi = ((size_t)b * L_SEQ + t) * D_DIM + col0 + wc * 32 + cg * 8;
        s8v x = *(const s8v*)&XE[xi];
        s8v o;
#pragma unroll
        for (int u = 0; u < 4; ++u) {
            o[u]     = (short)f2bf(fast_tanh(bf2f((unsigned short)x[u])     + v0[u]));
            o[u + 4] = (short)f2bf(fast_tanh(bf2f((unsigned short)x[u + 4]) + v1[u]));
        }
        *(s8v*)&XE[xi] = o;
    }
}

// ---------------------------------------------------------------------------
// k_mlp_mfma: h = tanh(concat(XE[i],XE[j]) @ W1 + b1) fused with rule-dot.
// 128x128 tile, K=2048, BK=64, swizzled LDS, depth-1 prefetch, XCD swizzle.
// ---------------------------------------------------------------------------
__global__ __launch_bounds__(256) void k_mlp_mfma(
    const int* __restrict__ i_idx, const int* __restrict__ j_idx,
    const bf16_t* __restrict__ XE, const bf16_t* __restrict__ W1T,
    const float* __restrict__ b1, const bf16_t* __restrict__ Wt2,
    const int* __restrict__ r_idx, float* __restrict__ partials)
{
    __shared__ bf16_t As[128 * 64];            // 16 KB
    __shared__ bf16_t Bs[128 * 64];            // 16 KB

    const int bi  = blockIdx.x;
    const int xcd = bi & 7, j = bi >> 3;
    const int rowTile = (xcd << 6) + (j >> 3);        // [0,512)
    const int colTile = j & 7;                        // [0,8)
    const int row0 = rowTile * 128, col0 = colTile * 128;

    const int tid = threadIdx.x;
    const int w = tid >> 6, l = tid & 63;
    const int q = l >> 4, t16 = l & 15;
    const int wm = (w >> 1) * 64, wn = (w & 1) * 64;

    const int rr = tid >> 2, c0 = tid & 3;
    const int sw0 = ((c0       ^ (rr & 7)) << 3);
    const int sw1 = (((c0 + 4) ^ (rr & 7)) << 3);

    const bf16_t* pi[2]; const bf16_t* pj[2];
#pragma unroll
    for (int r = 0; r < 2; ++r) {
        int m = row0 + rr + r * 64;
        pi[r] = XE + (size_t)i_idx[m] * D_DIM + c0 * 8;
        pj[r] = XE + (size_t)j_idx[m] * D_DIM - D_DIM + c0 * 8;  // k in [1024,2048)
    }
    const bf16_t* brow[2];
#pragma unroll
    for (int r = 0; r < 2; ++r)
        brow[r] = W1T + (size_t)(col0 + rr + r * 64) * (2 * D_DIM) + c0 * 8;

    f4v acc[4][4];
#pragma unroll
    for (int i = 0; i < 4; ++i)
#pragma unroll
        for (int jj = 0; jj < 4; ++jj) acc[i][jj] = (f4v)0.f;

    // prefetch chunk 0
    s8v a00 = *(const s8v*)(pi[0]);
    s8v a01 = *(const s8v*)(pi[0] + 32);
    s8v a10 = *(const s8v*)(pi[1]);
    s8v a11 = *(const s8v*)(pi[1] + 32);
    s8v b00 = *(const s8v*)(brow[0]);
    s8v b01 = *(const s8v*)(brow[0] + 32);
    s8v b10 = *(const s8v*)(brow[1]);
    s8v b11 = *(const s8v*)(brow[1] + 32);

    const int r7 = t16 & 7;
    for (int k0 = 0; k0 < 2 * D_DIM; k0 += 64) {
        __syncthreads();
        *(s8v*)&As[rr * 64 + sw0]        = a00;
        *(s8v*)&As[rr * 64 + sw1]        = a01;
        *(s8v*)&As[(rr + 64) * 64 + sw0] = a10;
        *(s8v*)&As[(rr + 64) * 64 + sw1] = a11;
        *(s8v*)&Bs[rr * 64 + sw0]        = b00;
        *(s8v*)&Bs[rr * 64 + sw1]        = b01;
        *(s8v*)&Bs[(rr + 64) * 64 + sw0] = b10;
        *(s8v*)&Bs[(rr + 64) * 64 + sw1] = b11;
        int kn = k0 + 64;
        if (kn < 2 * D_DIM) {
            const bf16_t* A0 = (kn < D_DIM) ? pi[0] : pj[0];
            const bf16_t* A1 = (kn < D_DIM) ? pi[1] : pj[1];
            a00 = *(const s8v*)(A0 + kn);
            a01 = *(const s8v*)(A0 + kn + 32);
            a10 = *(const s8v*)(A1 + kn);
            a11 = *(const s8v*)(A1 + kn + 32);
            b00 = *(const s8v*)(brow[0] + kn);
            b01 = *(const s8v*)(brow[0] + kn + 32);
            b10 = *(const s8v*)(brow[1] + kn);
            b11 = *(const s8v*)(brow[1] + kn + 32);
        }
        __syncthreads();
#pragma unroll
        for (int sub = 0; sub < 2; ++sub) {
            const int rsl = (((sub * 4 + q) ^ r7) << 3);
            s8v af[4], bfr[4];
#pragma unroll
            for (int ti = 0; ti < 4; ++ti)
                af[ti] = *(const s8v*)&As[(wm + ti * 16 + t16) * 64 + rsl];
#pragma unroll
            for (int tj = 0; tj < 4; ++tj)
                bfr[tj] = *(const s8v*)&Bs[(wn + tj * 16 + t16) * 64 + rsl];
#pragma unroll
            for (int ti = 0; ti < 4; ++ti)
#pragma unroll
                for (int tj = 0; tj < 4; ++tj)
                    acc[ti][tj] = mfma16(af[ti], bfr[tj], acc[ti][tj]);
        }
    }

    // fused epilogue in C-layout: fast_tanh, dot with gathered rule row, 16-lane reduce
    const int cb = colTile * 2 + (w & 1);
#pragma unroll
    for (int ti = 0; ti < 4; ++ti) {
#pragma unroll
        for (int rg = 0; rg < 4; ++rg) {
            int m = row0 + wm + ti * 16 + q * 4 + rg;
            int r = r_idx[m];
            const bf16_t* wrow = Wt2 + (size_t)r * D_DIM + col0 + wn + t16;
            float pd = 0.f;
#pragma unroll
            for (int tj = 0; tj < 4; ++tj) {
                int col = col0 + wn + tj * 16 + t16;
                float h = fast_tanh(acc[ti][tj][rg] + b1[col]);
                pd += h * bf2f(wrow[tj * 16]);
            }
            pd += __shfl_xor(pd, 1);
            pd += __shfl_xor(pd, 2);
            pd += __shfl_xor(pd, 4);
            pd += __shfl_xor(pd, 8);
            if (t16 == 0)
                partials[(size_t)cb * M_NODES + m] = pd;
        }
    }
}

// ---------------------------------------------------------------------------
__global__ __launch_bounds__(256) void k_reduce(
    const float* __restrict__ partials, const int* __restrict__ r_idx,
    const float* __restrict__ b2, float* __restrict__ out)
{
    int m = blockIdx.x * 256 + threadIdx.x;
    float s = 0.f;
#pragma unroll
    for (int cb = 0; cb < 16; ++cb)
        s += partials[(size_t)cb * M_NODES + m];
    out[m] = s + b2[r_idx[m]];
}

// ---------------------------------------------------------------------------
extern "C" void kernel_launch(void* const* d_in, const int* in_sizes, int n_in,
                              void* d_out, int out_size, void* d_ws, size_t ws_size,
                              hipStream_t stream) {
    const int*   tokens = (const int*)  d_in[0];
    const int*   i_idx  = (const int*)  d_in[1];
    const int*   j_idx  = (const int*)  d_in[2];
    const int*   r_idx  = (const int*)  d_in[3];
    const float* emb    = (const float*)d_in[4];
    const float* Wxh    = (const float*)d_in[5];
    const float* Whh    = (const float*)d_in[6];
    const float* bh     = (const float*)d_in[7];
    const float* h0     = (const float*)d_in[8];
    const float* W1     = (const float*)d_in[9];
    const float* b1     = (const float*)d_in[10];
    const float* W2     = (const float*)d_in[11];
    const float* b2     = (const float*)d_in[12];
    float* out = (float*)d_out;

    // Workspace (~156 MiB). embB (20 MiB) aliases WhhT/W1T/Wt2 (22 MiB):
    // embB dead after k_xw_mfma; those conversions run after it.
    bf16_t* XE   = (bf16_t*)d_ws;                        // [B*L][D]  128 MiB
    bf16_t* WxhT = XE   + (size_t)M_NODES * D_DIM;       // [D][D]      2 MiB
    bf16_t* WhhT = WxhT + (size_t)D_DIM * D_DIM;         // [D][D]      2 MiB
    bf16_t* W1T  = WhhT + (size_t)D_DIM * D_DIM;         // [D][2D]     4 MiB
    bf16_t* Wt2  = W1T  + (size_t)2 * D_DIM * D_DIM;     // [R][D]     16 MiB
    bf16_t* embB = WhhT;                                 // [V][D]     20 MiB (alias)
    bf16_t* h0b  = Wt2  + (size_t)R_RULES * D_DIM;       // [D] (pad 2048)
    float*  par  = (float*)(h0b + 2048);                 // [16][M]     4 MiB

    // Phase 1: emb->bf16, Wxh, h0
    k_cvt_emb<<<V_VOCAB * D_DIM / 2048, 256, 0, stream>>>(emb, embB);
    k_transcvt<<<dim3(D_DIM / 32, D_DIM / 32), dim3(32, 8), 0, stream>>>(Wxh, WxhT, D_DIM, D_DIM);
    k_cvt_h0<<<1, 256, 0, stream>>>(h0, h0b);

    // Phase 2: XE = bf16(embB[tokens] @ Wxh + bh)   (last reader of embB)
    k_xw_mfma<<<4096, 256, 0, stream>>>(tokens, embB, WxhT, bh, XE);

    // Phase 3: remaining weight conversions (overwrite embB region)
    k_transcvt<<<dim3(D_DIM / 32, D_DIM / 32), dim3(32, 8), 0, stream>>>(Whh, WhhT, D_DIM, D_DIM);
    k_transcvt<<<dim3(D_DIM / 32, 2 * D_DIM / 32), dim3(32, 8), 0, stream>>>(W1, W1T, 2 * D_DIM, D_DIM);
    k_transcvt<<<dim3(R_RULES / 32, D_DIM / 32), dim3(32, 8), 0, stream>>>(W2, Wt2, D_DIM, R_RULES);

    // Phase 4: 64 sequential RNN steps (in-place on XE)
    for (int t = 0; t < L_SEQ; ++t) {
        const bf16_t* Abase = (t == 0) ? h0b : (XE + (size_t)(t - 1) * D_DIM);
        int strideRow       = (t == 0) ? 0   : L_SEQ * D_DIM;
        k_step_mfma<<<dim3(B_BATCH / 64, D_DIM / 64), 256, 0, stream>>>(
            Abase, strideRow, WhhT, XE, t);
    }

    // Phase 5: MLP + fused rule-dot partials
    k_mlp_mfma<<<4096, 256, 0, stream>>>(
        i_idx, j_idx, XE, W1T, b1, Wt2, r_idx, par);

    // Phase 6: deterministic reduce + b2
    k_reduce<<<M_NODES / 256, 256, 0, stream>>>(par, r_idx, b2, out);
}